// Round 3
// baseline (431.753 us; speedup 1.0000x reference)
//
#include <hip/hip_runtime.h>

#define EPS_F 0.01f
#define LR_H  512
#define LR_W  512
#define HR_H  2048
#define HR_W  2048
#define NC    12   // N*C = 4*3

#define LR_PLANE (LR_H * LR_W)
#define HR_PLANE (HR_H * HR_W)

// One block = one plane x 4 consecutive HR rows.
// LR dependency chain: 4 HR rows -> mA/mb rows R..R+2 -> A/b rows R-1..R+3
// -> x/y rows R-2..R+4 (all edge-clamped, materialized in LDS so inner
// loops index without clamps).
#define XROWS 7
#define XW    516          // col c holds x[clamp(c-2)]
#define XSTR  517          // odd stride
#define AROWS 5
#define AW    514          // col j holds A[clamp(j-1)]
#define ASTR  515
#define MROWS 3
#define MW    513          // col j holds mA[min(j,511)] (dup last col)
#define MSTR  513

// smem layout (floats):
//   xs:  [0      .. 3618]   7*517
//   ys:  [3619   .. 7237]   7*517
//   As:  [7238   .. 9812]   5*515
//   Bs:  [9813   .. 12387]  5*515
//   mAs: overlay at 0    (3*513 = 1539)   -- xs dead by then
//   mbs: overlay at 1539 (3*513)
#define SMEM_FLOATS 12388

__global__ void __launch_bounds__(256) k_guided(
    const float* __restrict__ x, const float* __restrict__ y,
    const float* __restrict__ xhr, float* __restrict__ out) {
    __shared__ float smem[SMEM_FLOATS];
    float* xs  = smem;
    float* ys  = smem + 3619;
    float* As  = smem + 7238;
    float* Bs  = smem + 9813;
    float* mAs = smem;          // overlay
    float* mbs = smem + 1539;   // overlay

    const float scale = (float)(LR_H - 1) / (float)(HR_H - 1);

    // 6144 blocks; XCD-chunked swizzle (6144 % 8 == 0 -> bijective):
    // XCD k gets contiguous lin range [k*768, (k+1)*768) so consecutive
    // row-blocks (overlapping x/y windows) share an L2.
    int bid = blockIdx.x;
    int lin = (bid & 7) * 768 + (bid >> 3);
    int p   = lin >> 9;          // plane 0..11
    int rb  = lin & 511;         // row-block 0..511
    int R   = (int)((float)(4 * rb) * scale);  // floor(ph of first row)

    int tid = threadIdx.x;
    const float* xp = x + (size_t)p * LR_PLANE;
    const float* yp = y + (size_t)p * LR_PLANE;

    // ---- Phase 1: stage x,y rows clamp(R-2..R+4), cols clamp(-2..513) ----
    for (int r = 0; r < XROWS; ++r) {
        int gr = min(max(R - 2 + r, 0), LR_H - 1);
        const float* xrow = xp + gr * LR_W;
        const float* yrow = yp + gr * LR_W;
        for (int c = tid; c < XW; c += 256) {
            int gc = min(max(c - 2, 0), LR_W - 1);
            xs[r * XSTR + c] = xrow[gc];
            ys[r * XSTR + c] = yrow[gc];
        }
    }
    __syncthreads();

    // ---- Phase 2: A,b at rows clamp(R-1+q), cols clamp(j-1) ----
    // Tap x[clamp(qq+d)][clamp(pc+e)] == xs[(qq+d)-R+2][(pc+e)+2] (unclamped
    // offsets: clamping is materialized in the staged tile).
    for (int q = 0; q < AROWS; ++q) {
        int qq = min(max(R - 1 + q, 0), LR_H - 1);
        int rbase = (qq - R + 2) * XSTR;
        for (int j = tid; j < AW; j += 256) {
            int pc = min(max(j - 1, 0), LR_W - 1);
            int cbase = rbase + pc + 2;
            float sx = 0.f, sy = 0.f, sxy = 0.f, sxx = 0.f;
#pragma unroll
            for (int d = -1; d <= 1; ++d) {
                int ro = cbase + d * XSTR;
#pragma unroll
                for (int e = -1; e <= 1; ++e) {
                    float xv = xs[ro + e];
                    float yv = ys[ro + e];
                    sx  += xv;
                    sy  += yv;
                    sxy += xv * yv;
                    sxx += xv * xv;
                }
            }
            const float inv9 = 1.0f / 9.0f;
            float mx  = sx * inv9;
            float my  = sy * inv9;
            float cov = sxy * inv9 - mx * my;
            float var = sxx * inv9 - mx * mx;
            float Av  = cov / (var + EPS_F);
            As[q * ASTR + j] = Av;
            Bs[q * ASTR + j] = my - Av * mx;
        }
    }
    __syncthreads();   // As/Bs ready; xs/ys dead -> overlay allowed

    // ---- Phase 3: 3x3 box of A,b -> mAs rows min(R+t,511) ----
    for (int t = 0; t < MROWS; ++t) {
        int rr = min(R + t, LR_H - 1);
        // A row clamp(rr+d) lives at As[clamp(rr+d) - R + 1]
        int q0 = max(rr - 1, 0) - R + 1;
        int q1 = rr - R + 1;
        int q2 = min(rr + 1, LR_H - 1) - R + 1;
        for (int j = tid; j < MW; j += 256) {
            int cc = min(j, LR_W - 1);
            int c0 = cc;  // As col (cc+e)+1, e=-1 -> cc
            int r0 = q0 * ASTR + c0;
            int r1 = q1 * ASTR + c0;
            int r2 = q2 * ASTR + c0;
            float sA = 0.f, sB = 0.f;
            sA += As[r0] + As[r0 + 1] + As[r0 + 2];
            sA += As[r1] + As[r1 + 1] + As[r1 + 2];
            sA += As[r2] + As[r2 + 1] + As[r2 + 2];
            sB += Bs[r0] + Bs[r0 + 1] + Bs[r0 + 2];
            sB += Bs[r1] + Bs[r1 + 1] + Bs[r1 + 2];
            sB += Bs[r2] + Bs[r2 + 1] + Bs[r2 + 2];
            const float inv9 = 1.0f / 9.0f;
            mAs[t * MSTR + j] = sA * inv9;
            mbs[t * MSTR + j] = sB * inv9;
        }
    }
    __syncthreads();

    // ---- Phase 4: stream 4 HR rows: bilinear(mA,mb) * x_hr + clip ----
    const size_t hrbase = (size_t)p * HR_PLANE;
#pragma unroll
    for (int k = 0; k < 4; ++k) {
        int i = 4 * rb + k;
        float ph = (float)i * scale;
        int   i0 = (int)ph;
        float th = ph - (float)i0;
        int   i1 = min(i0 + 1, LR_H - 1);
        float omh = 1.0f - th;
        const float* a0 = mAs + (i0 - R) * MSTR;
        const float* a1 = mAs + (i1 - R) * MSTR;
        const float* b0 = mbs + (i0 - R) * MSTR;
        const float* b1 = mbs + (i1 - R) * MSTR;
        const float* xrow = xhr + hrbase + (size_t)i * HR_W;
        float*       orow = out + hrbase + (size_t)i * HR_W;

#pragma unroll
        for (int g = 0; g < 2; ++g) {
            int j = (tid + g * 256) * 4;
            const float4 xv = *(const float4*)(xrow + j);
            float xin[4] = {xv.x, xv.y, xv.z, xv.w};
            float r[4];
#pragma unroll
            for (int kk = 0; kk < 4; ++kk) {
                float pw = (float)(j + kk) * scale;
                int   j0 = (int)pw;
                float tw = pw - (float)j0;
                float omw = 1.0f - tw;
                // identical op order to the verified two-kernel version:
                // H-lerp first, then W-lerp
                float ha0 = a0[j0]     * omh + a1[j0]     * th;
                float ha1 = a0[j0 + 1] * omh + a1[j0 + 1] * th;
                float hb0 = b0[j0]     * omh + b1[j0]     * th;
                float hb1 = b0[j0 + 1] * omh + b1[j0 + 1] * th;
                float a  = ha0 * omw + ha1 * tw;
                float bb = hb0 * omw + hb1 * tw;
                float v  = a * xin[kk] + bb;
                r[kk] = fminf(fmaxf(v, 0.0f), 255.0f);
            }
            float4 o;
            o.x = r[0]; o.y = r[1]; o.z = r[2]; o.w = r[3];
            *(float4*)(orow + j) = o;
        }
    }
}

extern "C" void kernel_launch(void* const* d_in, const int* in_sizes, int n_in,
                              void* d_out, int out_size, void* d_ws, size_t ws_size,
                              hipStream_t stream) {
    const float* x_lr = (const float*)d_in[0];
    const float* y_lr = (const float*)d_in[1];
    const float* x_hr = (const float*)d_in[2];
    float* out = (float*)d_out;
    (void)d_ws; (void)ws_size;

    int threads = 256;
    int blocks  = NC * (HR_H / 4);   // 12 * 512 = 6144
    k_guided<<<blocks, threads, 0, stream>>>(x_lr, y_lr, x_hr, out);
}

// Round 5
// 368.879 us; speedup vs baseline: 1.1704x; 1.1704x over previous
//
#include <hip/hip_runtime.h>

#define RAD   1
#define EPS_F 0.01f
#define LR_H  512
#define LR_W  512
#define HR_H  2048
#define HR_W  2048
#define NC    12   // N*C = 4*3

#define LR_PLANE (LR_H * LR_W)
#define HR_PLANE (HR_H * HR_W)
#define LR_TOTAL (NC * LR_PLANE)
#define HR_TOTAL (NC * HR_PLANE)

// native clang vector type: __builtin_nontemporal_store requires a
// pointer to scalar/vector type, not HIP's struct-based float4.
typedef float vfloat4 __attribute__((ext_vector_type(4)));

// ---- fused LR pass: stats -> A,b -> 3x3 box -> mA,mb, all in LDS ----
// One block = one 32x32 output tile. Halo x/y tile 36x36, A/b tile 34x34.
#define TILE 32
#define XT   (TILE + 4)   // 36
#define XSTR (XT + 1)     // 37 (odd stride: no bank conflicts)
#define AT   (TILE + 2)   // 34
#define ASTR (AT + 1)     // 35

__global__ void __launch_bounds__(256) k_fused_lr(
    const float* __restrict__ x, const float* __restrict__ y,
    float* __restrict__ mA, float* __restrict__ mb) {
    __shared__ float xs[XT * XSTR];
    __shared__ float ys[XT * XSTR];
    __shared__ float As[AT * ASTR];
    __shared__ float Bs[AT * ASTR];

    int bid = blockIdx.x;
    int p   = bid >> 8;          // plane (16x16 tiles per plane)
    int rem = bid & 255;
    int ty  = rem >> 4, tx = rem & 15;
    int oy  = ty * TILE, ox = tx * TILE;
    const float* xp = x + (size_t)p * LR_PLANE;
    const float* yp = y + (size_t)p * LR_PLANE;
    int tid = threadIdx.x;

    // Stage x,y halo tile (rows/cols oy-2..oy+33 clamped). xs[k] holds
    // x[clamp(oy+k-2)], so replicated edge rows are materialized.
    for (int i = tid; i < XT * XT; i += 256) {
        int r  = i / XT, c = i - r * XT;
        int gr = min(max(oy + r - 2, 0), LR_H - 1);
        int gc = min(max(ox + c - 2, 0), LR_W - 1);
        xs[r * XSTR + c] = xp[gr * LR_W + gc];
        ys[r * XSTR + c] = yp[gr * LR_W + gc];
    }
    __syncthreads();

    // A,b at the 34x34 CLAMPED positions q=clamp(oy+k-1), pc=clamp(ox+c-1).
    // Stats taps are x[clamp(q+d)][clamp(pc+e)]; map into xs via
    // lds_row = clamp(q+d) - oy + 2 (always in [0,35]).
    for (int i = tid; i < AT * AT; i += 256) {
        int k  = i / AT, c = i - k * AT;
        int q  = min(max(oy + k - 1, 0), LR_H - 1);
        int pc = min(max(ox + c - 1, 0), LR_W - 1);
        int rows[3] = { max(q - 1, 0)         - oy + 2,
                        q                     - oy + 2,
                        min(q + 1, LR_H - 1)  - oy + 2 };
        int cols[3] = { max(pc - 1, 0)        - ox + 2,
                        pc                    - ox + 2,
                        min(pc + 1, LR_W - 1) - ox + 2 };
        float sx = 0.f, sy = 0.f, sxy = 0.f, sxx = 0.f;
#pragma unroll
        for (int a = 0; a < 3; ++a) {
            int ro = rows[a] * XSTR;
#pragma unroll
            for (int b2 = 0; b2 < 3; ++b2) {
                float xv = xs[ro + cols[b2]];
                float yv = ys[ro + cols[b2]];
                sx  += xv;
                sy  += yv;
                sxy += xv * yv;
                sxx += xv * xv;
            }
        }
        const float inv9 = 1.0f / 9.0f;
        float mx  = sx * inv9;
        float my  = sy * inv9;
        float cov = sxy * inv9 - mx * my;
        float var = sxx * inv9 - mx * mx;
        float Av  = cov / (var + EPS_F);
        As[k * ASTR + c] = Av;
        Bs[k * ASTR + c] = my - Av * mx;
    }
    __syncthreads();

    // 3x3 box of A,b -> 32x32 outputs. As already holds edge-replicated
    // values, so taps are simply As[r+a][c+b].
    float* mAp = mA + (size_t)p * LR_PLANE;
    float* mbp = mb + (size_t)p * LR_PLANE;
    for (int i = tid; i < TILE * TILE; i += 256) {
        int r = i >> 5, c = i & 31;
        float sA = 0.f, sB = 0.f;
#pragma unroll
        for (int a = 0; a < 3; ++a) {
            int ro = (r + a) * ASTR + c;
#pragma unroll
            for (int b2 = 0; b2 < 3; ++b2) {
                sA += As[ro + b2];
                sB += Bs[ro + b2];
            }
        }
        const float inv9 = 1.0f / 9.0f;
        mAp[(size_t)(oy + r) * LR_W + (ox + c)] = sA * inv9;
        mbp[(size_t)(oy + r) * LR_W + (ox + c)] = sB * inv9;
    }
}

// K3: one block per (plane, HR row). Stage H-lerped LR rows of mA/mb in
// LDS, then per-pixel W-lerp + fused FMA/clip. Output stores are
// NON-TEMPORAL so the 201 MB `out` stream stops evicting x_hr from the
// 256 MiB Infinity Cache (x_hr = 192 MiB, fits; round-3 counters showed
// L3 already absorbing ~45% of x_hr fetches even while being thrashed).
__global__ void __launch_bounds__(256) k_upsample_fuse(
    const float* __restrict__ mA, const float* __restrict__ mb,
    const float* __restrict__ xhr, float* __restrict__ out) {
    __shared__ float hA[513];
    __shared__ float hb[513];

    int bid = blockIdx.x;                 // plane * HR_H + i
    int i     = bid & (HR_H - 1);
    int plane = bid >> 11;

    const float scale = (float)(LR_H - 1) / (float)(HR_H - 1);

    float ph = i * scale;
    int   i0 = (int)ph;
    int   i1 = min(i0 + 1, LR_H - 1);
    float th = ph - (float)i0;
    float omh = 1.0f - th;

    const float* Ap = mA + (size_t)plane * LR_PLANE;
    const float* bp = mb + (size_t)plane * LR_PLANE;
    int tid = threadIdx.x;

    for (int c = tid; c < 513; c += 256) {
        int col = min(c, LR_W - 1);
        float a0 = Ap[i0 * LR_W + col];
        float a1 = Ap[i1 * LR_W + col];
        float b0 = bp[i0 * LR_W + col];
        float b1 = bp[i1 * LR_W + col];
        hA[c] = a0 * omh + a1 * th;
        hb[c] = b0 * omh + b1 * th;
    }
    __syncthreads();

    const float* xrow = xhr + (size_t)plane * HR_PLANE + (size_t)i * HR_W;
    float*       orow = out + (size_t)plane * HR_PLANE + (size_t)i * HR_W;

#pragma unroll
    for (int g = 0; g < 2; ++g) {
        int j = (tid + g * 256) * 4;
        const vfloat4 xv = *(const vfloat4*)(xrow + j);
        float xin[4] = {xv.x, xv.y, xv.z, xv.w};
        float r[4];
#pragma unroll
        for (int k = 0; k < 4; ++k) {
            float pw = (float)(j + k) * scale;
            int   j0 = (int)pw;
            float tw = pw - (float)j0;
            float omw = 1.0f - tw;
            float a  = hA[j0] * omw + hA[j0 + 1] * tw;
            float bb = hb[j0] * omw + hb[j0 + 1] * tw;
            float v  = a * xin[k] + bb;
            r[k] = fminf(fmaxf(v, 0.0f), 255.0f);
        }
        vfloat4 o;
        o.x = r[0]; o.y = r[1]; o.z = r[2]; o.w = r[3];
        __builtin_nontemporal_store(o, (vfloat4*)(orow + j));
    }
}

extern "C" void kernel_launch(void* const* d_in, const int* in_sizes, int n_in,
                              void* d_out, int out_size, void* d_ws, size_t ws_size,
                              hipStream_t stream) {
    const float* x_lr = (const float*)d_in[0];
    const float* y_lr = (const float*)d_in[1];
    const float* x_hr = (const float*)d_in[2];
    float* out = (float*)d_out;

    float* mA = (float*)d_ws;
    float* mb = mA + LR_TOTAL;

    {
        int threads = 256;
        int blocks = NC * 16 * 16;         // one block per 32x32 LR tile
        k_fused_lr<<<blocks, threads, 0, stream>>>(x_lr, y_lr, mA, mb);
    }
    {
        int threads = 256;
        int blocks = NC * HR_H;            // one block per HR row per plane
        k_upsample_fuse<<<blocks, threads, 0, stream>>>(mA, mb, x_hr, out);
    }
}